// Round 8
// baseline (1918.085 us; speedup 1.0000x reference)
//
#include <hip/hip_runtime.h>

#define N_NODES 50000
#define N_EDGES 1600000
#define NB 128
#define GB 782            // ceil(N/64)
#define P1B 196           // pass-1 blocks, 8192 edges each
#define P1E 8192
#define NBUCK 196         // dst >> 8 (256 nodes per bucket)
#define TOTG (NBUCK * P1B)   // 38416
#define SCB 151              // ceil(TOTG/256)

__device__ __forceinline__ unsigned short f2bf(float f) {
    unsigned u = __float_as_uint(f);
    unsigned r = (u + 0x7FFFu + ((u >> 16) & 1u)) >> 16;   // RNE
    return (unsigned short)r;
}

// ---------- CSR build: two-phase radix partition ----------
__global__ __launch_bounds__(256) void k_p1hist(
    const int* __restrict__ dst, int* __restrict__ gcount) {
    __shared__ int hist[NBUCK];
    int tid = threadIdx.x;
    if (tid < NBUCK) hist[tid] = 0;
    __syncthreads();
    int base = blockIdx.x * P1E;
    for (int k = 0; k < P1E; k += 256) {
        int e = base + k + tid;
        if (e < N_EDGES) atomicAdd(&hist[dst[e] >> 8], 1);
    }
    __syncthreads();
    if (tid < NBUCK) gcount[tid * P1B + blockIdx.x] = hist[tid];
}

__global__ __launch_bounds__(256) void k_scanA(
    const int* __restrict__ gcount, int* __restrict__ bsum) {
    int i = blockIdx.x * 256 + threadIdx.x;
    int v = (i < TOTG) ? gcount[i] : 0;
#pragma unroll
    for (int off = 1; off < 64; off <<= 1) v += __shfl_xor(v, off);
    __shared__ int ws[4];
    if ((threadIdx.x & 63) == 0) ws[threadIdx.x >> 6] = v;
    __syncthreads();
    if (threadIdx.x == 0) bsum[blockIdx.x] = ws[0] + ws[1] + ws[2] + ws[3];
}

__global__ __launch_bounds__(256) void k_scanB(
    const int* __restrict__ bsum, int* __restrict__ boff, int* __restrict__ row_ptr) {
    __shared__ int s[256];
    int t = threadIdx.x;
    int v = (t < SCB) ? bsum[t] : 0;
    s[t] = v;
    __syncthreads();
    for (int off = 1; off < 256; off <<= 1) {
        int x = s[t];
        int y = (t >= off) ? s[t - off] : 0;
        __syncthreads();
        s[t] = x + y;
        __syncthreads();
    }
    if (t < SCB) boff[t] = s[t] - v;
    if (t == 255) row_ptr[N_NODES] = s[255];
}

__global__ __launch_bounds__(256) void k_scanC(
    int* __restrict__ gcount, const int* __restrict__ boff) {
    __shared__ int s[256];
    int t = threadIdx.x;
    int i = blockIdx.x * 256 + t;
    int v = (i < TOTG) ? gcount[i] : 0;
    s[t] = v;
    __syncthreads();
    for (int off = 1; off < 256; off <<= 1) {
        int x = s[t];
        int y = (t >= off) ? s[t - off] : 0;
        __syncthreads();
        s[t] = x + y;
        __syncthreads();
    }
    if (i < TOTG) gcount[i] = s[t] - v + boff[blockIdx.x];
}

__global__ __launch_bounds__(256) void k_p1scat(
    const int* __restrict__ src, const int* __restrict__ dst,
    const int* __restrict__ goff, unsigned* __restrict__ tmp) {
    __shared__ int cur[NBUCK];
    int tid = threadIdx.x;
    if (tid < NBUCK) cur[tid] = goff[tid * P1B + blockIdx.x];
    __syncthreads();
    int base = blockIdx.x * P1E;
    for (int k = 0; k < P1E; k += 256) {
        int e = base + k + tid;
        if (e < N_EDGES) {
            int d = dst[e];
            int pos = atomicAdd(&cur[d >> 8], 1);
            tmp[pos] = ((unsigned)(d & 255) << 16) | (unsigned)src[e];
        }
    }
}

__global__ __launch_bounds__(256) void k_p2(
    const unsigned* __restrict__ tmp, const int* __restrict__ goff,
    int* __restrict__ row_ptr, unsigned short* __restrict__ csr_src) {
    __shared__ int nh[256];
    __shared__ int ps[256];
    int b = blockIdx.x, tid = threadIdx.x;
    int base = goff[b * P1B];
    int endv = (b == NBUCK - 1) ? N_EDGES : goff[(b + 1) * P1B];
    int cnt = endv - base;
    nh[tid] = 0;
    __syncthreads();
    for (int i = tid; i < cnt; i += 256)
        atomicAdd(&nh[tmp[base + i] >> 16], 1);
    __syncthreads();
    int deg = nh[tid];
    ps[tid] = deg;
    __syncthreads();
    for (int off = 1; off < 256; off <<= 1) {
        int x = ps[tid];
        int y = (tid >= off) ? ps[tid - off] : 0;
        __syncthreads();
        ps[tid] = x + y;
        __syncthreads();
    }
    int ex = ps[tid] - deg;
    int node = (b << 8) + tid;
    if (node < N_NODES) row_ptr[node] = base + ex;
    __syncthreads();
    nh[tid] = ex;   // cursor
    __syncthreads();
    for (int i = tid; i < cnt; i += 256) {
        unsigned u = tmp[base + i];
        int pos = atomicAdd(&nh[u >> 16], 1);
        csr_src[base + pos] = (unsigned short)(u & 0xFFFFu);
    }
}

// vn = pooled = broadcast(vn_emb)
__global__ __launch_bounds__(256) void k_vn_init(
    const float* __restrict__ vn_emb, float* __restrict__ vn,
    float* __restrict__ pooled) {
    int t = blockIdx.x * 256 + threadIdx.x;
    float v = vn_emb[t & 63];
    vn[t] = v;
    pooled[t] = v;
}

// agg[d] = (1+eps[l])*h[d] + sum over csr row of relu(h[src]); h stored bf16 (hb)
// one wave per node; lane = (e8 = lane>>3 edge slot, cg = lane&7 channel group)
__global__ __launch_bounds__(256) void k_agg(
    const unsigned short* __restrict__ hb,
    const int* __restrict__ row_ptr, const unsigned short* __restrict__ csr_src,
    float* __restrict__ agg, const float* __restrict__ eps, int l) {
    int wave = threadIdx.x >> 6, lane = threadIdx.x & 63;
    int node = blockIdx.x * 4 + wave;
    int s0 = row_ptr[node], s1 = row_ptr[node + 1];
    int e8 = lane >> 3, cg = lane & 7;
    float acc[8] = {0.f, 0.f, 0.f, 0.f, 0.f, 0.f, 0.f, 0.f};
    for (int e = s0 + e8; e < s1; e += 8) {
        int sidx = (int)csr_src[e];
        uint4 pk = *(const uint4*)(hb + (size_t)sidx * 64 + cg * 8);
        acc[0] += fmaxf(__uint_as_float(pk.x << 16), 0.f);
        acc[1] += fmaxf(__uint_as_float(pk.x & 0xFFFF0000u), 0.f);
        acc[2] += fmaxf(__uint_as_float(pk.y << 16), 0.f);
        acc[3] += fmaxf(__uint_as_float(pk.y & 0xFFFF0000u), 0.f);
        acc[4] += fmaxf(__uint_as_float(pk.z << 16), 0.f);
        acc[5] += fmaxf(__uint_as_float(pk.z & 0xFFFF0000u), 0.f);
        acc[6] += fmaxf(__uint_as_float(pk.w << 16), 0.f);
        acc[7] += fmaxf(__uint_as_float(pk.w & 0xFFFF0000u), 0.f);
    }
#pragma unroll
    for (int off = 8; off < 64; off <<= 1) {
#pragma unroll
        for (int c = 0; c < 8; ++c)
            acc[c] += __shfl_xor(acc[c], off);
    }
    if (e8 == 0) {
        float se = 1.0f + eps[l];
        uint4 hp = *(const uint4*)(hb + (size_t)node * 64 + cg * 8);
        float* ap = agg + (size_t)node * 64 + cg * 8;
        float4 o0, o1;
        o0.x = se * __uint_as_float(hp.x << 16)          + acc[0];
        o0.y = se * __uint_as_float(hp.x & 0xFFFF0000u)  + acc[1];
        o0.z = se * __uint_as_float(hp.y << 16)          + acc[2];
        o0.w = se * __uint_as_float(hp.y & 0xFFFF0000u)  + acc[3];
        o1.x = se * __uint_as_float(hp.z << 16)          + acc[4];
        o1.y = se * __uint_as_float(hp.z & 0xFFFF0000u)  + acc[5];
        o1.z = se * __uint_as_float(hp.w << 16)          + acc[6];
        o1.w = se * __uint_as_float(hp.w & 0xFFFF0000u)  + acc[7];
        *(float4*)(ap) = o0;
        *(float4*)(ap + 4) = o1;
    }
}

// GEMM + fused pre epilogue (compile-time specialized):
// o = HAS_BN ? relu(BN(in@W+bias)) : in@W+bias
// hv = o + vn[batch]; out = OUT_INIT ? hv : out+hv
// if FULL: hb = bf16(hv), pooled += segment_sum(hv)
template <int HAS_BN, int OUT_INIT, int FULL>
__global__ __launch_bounds__(256, 4) void k_gemm_pre(
    const float* __restrict__ in, const float* __restrict__ W,
    const float* __restrict__ bias,
    const float* __restrict__ g, const float* __restrict__ be,
    const float* __restrict__ m, const float* __restrict__ v,
    const float* __restrict__ vn, const int* __restrict__ batch_id,
    unsigned short* __restrict__ hb, float* __restrict__ out,
    float* __restrict__ pooled) {
    __shared__ float sW[64 * 64];
    __shared__ float sIn[64 * 68];
    int tid = threadIdx.x;
    int row0 = blockIdx.x * 64;
#pragma unroll
    for (int i = 0; i < 4; ++i)
        ((float4*)sW)[tid + 256 * i] = ((const float4*)W)[tid + 256 * i];
#pragma unroll
    for (int i = 0; i < 4; ++i) {
        int idx = tid + 256 * i;
        int r = idx >> 4, j = idx & 15;
        float4 val = make_float4(0.f, 0.f, 0.f, 0.f);
        if (row0 + r < N_NODES) val = ((const float4*)in)[(size_t)(row0 + r) * 16 + j];
        ((float4*)(sIn + r * 68))[j] = val;
    }
    __syncthreads();
    int c4 = (tid & 15) * 4;
    int rl = (tid >> 4) * 4;
    float acc[4][4] = {{0.f}};
    for (int k = 0; k < 64; k += 4) {
        float4 a[4];
#pragma unroll
        for (int i = 0; i < 4; ++i) a[i] = *(const float4*)(sIn + (rl + i) * 68 + k);
#pragma unroll
        for (int kk = 0; kk < 4; ++kk) {
            float4 wv = *(const float4*)(sW + (k + kk) * 64 + c4);
#pragma unroll
            for (int i = 0; i < 4; ++i) {
                float av = kk == 0 ? a[i].x : kk == 1 ? a[i].y : kk == 2 ? a[i].z : a[i].w;
                acc[i][0] += av * wv.x; acc[i][1] += av * wv.y;
                acc[i][2] += av * wv.z; acc[i][3] += av * wv.w;
            }
        }
    }
    float scl[4], shf[4];
#pragma unroll
    for (int j = 0; j < 4; ++j) {
        int c = c4 + j;
        if (HAS_BN) {
            float sc = g[c] * rsqrtf(v[c] + 1e-5f);
            scl[j] = sc;
            shf[j] = be[c] - m[c] * sc + bias[c] * sc;
        } else {
            scl[j] = 1.0f;
            shf[j] = bias[c];
        }
    }
    // ---- fused pre epilogue ----
    __syncthreads();                     // all GEMM reads of sIn done
    float* sP = sIn;                     // [16][64] pool partials
    int* sBid = (int*)(sIn + 1024);      // 64 ints
    if (tid < 64) {
        int row = row0 + tid;
        sBid[tid] = batch_id[row < N_NODES ? row : (N_NODES - 1)];
    }
    __syncthreads();
    bool fast = (sBid[0] == sBid[63]);
    float4 psum = make_float4(0.f, 0.f, 0.f, 0.f);
#pragma unroll
    for (int i = 0; i < 4; ++i) {
        int row = row0 + rl + i;
        if (row >= N_NODES) continue;
        float o0 = acc[i][0] * scl[0] + shf[0];
        float o1 = acc[i][1] * scl[1] + shf[1];
        float o2 = acc[i][2] * scl[2] + shf[2];
        float o3 = acc[i][3] * scl[3] + shf[3];
        if (HAS_BN) {
            o0 = fmaxf(o0, 0.f); o1 = fmaxf(o1, 0.f);
            o2 = fmaxf(o2, 0.f); o3 = fmaxf(o3, 0.f);
        }
        int b = sBid[rl + i];
        float4 vnv = *(const float4*)(vn + b * 64 + c4);
        float4 hv = make_float4(o0 + vnv.x, o1 + vnv.y, o2 + vnv.z, o3 + vnv.w);
        if (OUT_INIT) {
            *(float4*)(out + (size_t)row * 64 + c4) = hv;
        } else {
            float4 ov = *(const float4*)(out + (size_t)row * 64 + c4);
            ov.x += hv.x; ov.y += hv.y; ov.z += hv.z; ov.w += hv.w;
            *(float4*)(out + (size_t)row * 64 + c4) = ov;
        }
        if (FULL) {
            ushort4 rb;
            rb.x = f2bf(hv.x); rb.y = f2bf(hv.y);
            rb.z = f2bf(hv.z); rb.w = f2bf(hv.w);
            *(ushort4*)(hb + (size_t)row * 64 + c4) = rb;
            if (fast) {
                psum.x += hv.x; psum.y += hv.y; psum.z += hv.z; psum.w += hv.w;
            } else {
                atomicAdd(&pooled[b * 64 + c4 + 0], hv.x);
                atomicAdd(&pooled[b * 64 + c4 + 1], hv.y);
                atomicAdd(&pooled[b * 64 + c4 + 2], hv.z);
                atomicAdd(&pooled[b * 64 + c4 + 3], hv.w);
            }
        }
    }
    if (FULL && fast) {
        *(float4*)(sP + (tid >> 4) * 64 + c4) = psum;
        __syncthreads();
        if (tid < 64) {
            float s = 0.f;
#pragma unroll
            for (int r = 0; r < 16; ++r) s += sP[r * 64 + tid];
            atomicAdd(&pooled[sBid[0] * 64 + tid], s);
        }
    }
}

// GIN stage 1: z1 = relu(BN1(agg@W1+b1)); block GB runs the vn MLP
__global__ __launch_bounds__(256) void k_gemm1vn(
    const float* __restrict__ in, const float* __restrict__ W,
    const float* __restrict__ bias, const float* __restrict__ g,
    const float* __restrict__ be, const float* __restrict__ m,
    const float* __restrict__ v, float* __restrict__ out,
    const float* __restrict__ pooled,
    const float* __restrict__ W1, const float* __restrict__ b1,
    const float* __restrict__ g1, const float* __restrict__ be1,
    const float* __restrict__ m1, const float* __restrict__ v1,
    const float* __restrict__ W2, const float* __restrict__ b2,
    const float* __restrict__ g2, const float* __restrict__ be2,
    const float* __restrict__ m2, const float* __restrict__ v2,
    float* __restrict__ vn_out, float* __restrict__ pooled_out) {
    __shared__ float sW[64 * 64];
    __shared__ float sIn[64 * 68];
    int tid = threadIdx.x;
    int c4 = (tid & 15) * 4;
    int rl = (tid >> 4) * 4;

    if (blockIdx.x == GB) {
        for (int ph = 0; ph < 2; ++ph) {
#pragma unroll
            for (int i = 0; i < 4; ++i)
                ((float4*)sW)[tid + 256 * i] = ((const float4*)W1)[tid + 256 * i];
#pragma unroll
            for (int i = 0; i < 4; ++i) {
                int idx = tid + 256 * i;
                int r = idx >> 4, j = idx & 15;
                ((float4*)(sIn + r * 68))[j] = ((const float4*)pooled)[(ph * 64 + r) * 16 + j];
            }
            __syncthreads();
            float acc[4][4] = {{0.f}};
#pragma unroll 8
            for (int k = 0; k < 64; ++k) {
                float4 w = *(const float4*)(sW + k * 64 + c4);
#pragma unroll
                for (int i = 0; i < 4; ++i) {
                    float a = sIn[(rl + i) * 68 + k];
                    acc[i][0] += a * w.x; acc[i][1] += a * w.y;
                    acc[i][2] += a * w.z; acc[i][3] += a * w.w;
                }
            }
            float scl[4], shf[4];
#pragma unroll
            for (int j = 0; j < 4; ++j) {
                int c = c4 + j;
                float sc = g1[c] * rsqrtf(v1[c] + 1e-5f);
                scl[j] = sc;
                shf[j] = be1[c] - m1[c] * sc + b1[c] * sc;
            }
            __syncthreads();
#pragma unroll
            for (int i = 0; i < 4; ++i)
#pragma unroll
                for (int j = 0; j < 4; ++j)
                    sIn[(rl + i) * 68 + c4 + j] = fmaxf(acc[i][j] * scl[j] + shf[j], 0.f);
#pragma unroll
            for (int i = 0; i < 4; ++i)
                ((float4*)sW)[tid + 256 * i] = ((const float4*)W2)[tid + 256 * i];
            __syncthreads();
            float acc2[4][4] = {{0.f}};
#pragma unroll 8
            for (int k = 0; k < 64; ++k) {
                float4 w = *(const float4*)(sW + k * 64 + c4);
#pragma unroll
                for (int i = 0; i < 4; ++i) {
                    float a = sIn[(rl + i) * 68 + k];
                    acc2[i][0] += a * w.x; acc2[i][1] += a * w.y;
                    acc2[i][2] += a * w.z; acc2[i][3] += a * w.w;
                }
            }
#pragma unroll
            for (int j = 0; j < 4; ++j) {
                int c = c4 + j;
                float sc = g2[c] * rsqrtf(v2[c] + 1e-5f);
                scl[j] = sc;
                shf[j] = be2[c] - m2[c] * sc + b2[c] * sc;
            }
#pragma unroll
            for (int i = 0; i < 4; ++i) {
                int row = ph * 64 + rl + i;
                float4 o;
                o.x = fmaxf(acc2[i][0] * scl[0] + shf[0], 0.f);
                o.y = fmaxf(acc2[i][1] * scl[1] + shf[1], 0.f);
                o.z = fmaxf(acc2[i][2] * scl[2] + shf[2], 0.f);
                o.w = fmaxf(acc2[i][3] * scl[3] + shf[3], 0.f);
                *(float4*)(vn_out + row * 64 + c4) = o;
                *(float4*)(pooled_out + row * 64 + c4) = o;
            }
            __syncthreads();
        }
        return;
    }

    int row0 = blockIdx.x * 64;
#pragma unroll
    for (int i = 0; i < 4; ++i)
        ((float4*)sW)[tid + 256 * i] = ((const float4*)W)[tid + 256 * i];
#pragma unroll
    for (int i = 0; i < 4; ++i) {
        int idx = tid + 256 * i;
        int r = idx >> 4, j = idx & 15;
        float4 val = make_float4(0.f, 0.f, 0.f, 0.f);
        if (row0 + r < N_NODES) val = ((const float4*)in)[(size_t)(row0 + r) * 16 + j];
        ((float4*)(sIn + r * 68))[j] = val;
    }
    __syncthreads();
    float acc[4][4] = {{0.f}};
    for (int k = 0; k < 64; k += 4) {
        float4 a[4];
#pragma unroll
        for (int i = 0; i < 4; ++i) a[i] = *(const float4*)(sIn + (rl + i) * 68 + k);
#pragma unroll
        for (int kk = 0; kk < 4; ++kk) {
            float4 wv = *(const float4*)(sW + (k + kk) * 64 + c4);
#pragma unroll
            for (int i = 0; i < 4; ++i) {
                float av = kk == 0 ? a[i].x : kk == 1 ? a[i].y : kk == 2 ? a[i].z : a[i].w;
                acc[i][0] += av * wv.x; acc[i][1] += av * wv.y;
                acc[i][2] += av * wv.z; acc[i][3] += av * wv.w;
            }
        }
    }
    float scl[4], shf[4];
#pragma unroll
    for (int j = 0; j < 4; ++j) {
        int c = c4 + j;
        float sc = g[c] * rsqrtf(v[c] + 1e-5f);
        scl[j] = sc;
        shf[j] = be[c] - m[c] * sc + bias[c] * sc;
    }
#pragma unroll
    for (int r = 0; r < 4; ++r) {
        int row = row0 + rl + r;
        if (row < N_NODES) {
            float4 o;
            o.x = fmaxf(acc[r][0] * scl[0] + shf[0], 0.f);
            o.y = fmaxf(acc[r][1] * scl[1] + shf[1], 0.f);
            o.z = fmaxf(acc[r][2] * scl[2] + shf[2], 0.f);
            o.w = fmaxf(acc[r][3] * scl[3] + shf[3], 0.f);
            *(float4*)(out + (size_t)row * 64 + c4) = o;
        }
    }
}

extern "C" void kernel_launch(void* const* d_in, const int* in_sizes, int n_in,
                              void* d_out, int out_size, void* d_ws, size_t ws_size,
                              hipStream_t stream) {
    const float* x      = (const float*)d_in[0];
    const float* lin_W  = (const float*)d_in[1];
    const float* lin_b  = (const float*)d_in[2];
    const float* eps    = (const float*)d_in[3];
    const float* gin_W1 = (const float*)d_in[4];
    const float* gin_b1 = (const float*)d_in[5];
    const float* gbn_g  = (const float*)d_in[6];
    const float* gbn_b  = (const float*)d_in[7];
    const float* gbn_m  = (const float*)d_in[8];
    const float* gbn_v  = (const float*)d_in[9];
    const float* gin_W2 = (const float*)d_in[10];
    const float* gin_b2 = (const float*)d_in[11];
    const float* bn_g   = (const float*)d_in[12];
    const float* bn_b   = (const float*)d_in[13];
    const float* bn_m   = (const float*)d_in[14];
    const float* bn_v   = (const float*)d_in[15];
    const float* vn_emb = (const float*)d_in[16];
    const float* vn_W1  = (const float*)d_in[17];
    const float* vn_b1  = (const float*)d_in[18];
    const float* v1g    = (const float*)d_in[19];
    const float* v1b    = (const float*)d_in[20];
    const float* v1m    = (const float*)d_in[21];
    const float* v1v    = (const float*)d_in[22];
    const float* vn_W2  = (const float*)d_in[23];
    const float* vn_b2  = (const float*)d_in[24];
    const float* v2g    = (const float*)d_in[25];
    const float* v2b    = (const float*)d_in[26];
    const float* v2m    = (const float*)d_in[27];
    const float* v2v    = (const float*)d_in[28];
    const int* src      = (const int*)d_in[29];
    const int* dst      = (const int*)d_in[30];
    const int* batch_id = (const int*)d_in[31];
    float* out = (float*)d_out;

    // workspace layout (16B-aligned regions)
    unsigned short* hb = (unsigned short*)d_ws;            // N*64 bf16 (h)
    float* z1     = (float*)(hb + (size_t)N_NODES * 64);   // N*64 f32
    float* agg    = z1 + (size_t)N_NODES * 64;             // N*64 f32
    float* vn     = agg + (size_t)N_NODES * 64;            // B*64
    float* pooled = vn + (size_t)NB * 64;                  // B*64
    int*   gcount  = (int*)(pooled + (size_t)NB * 64);     // TOTG
    int*   row_ptr = gcount + TOTG;                        // N+1
    int*   bsum    = row_ptr + N_NODES + 2;                // 256
    int*   boff    = bsum + 256;                           // 256
    unsigned* tmp  = (unsigned*)(boff + 256);              // E u32
    unsigned short* csr_src = (unsigned short*)(tmp + N_EDGES); // E ushort

    // ---- CSR build (radix partition; single-owner final writes) ----
    k_p1hist<<<P1B, 256, 0, stream>>>(dst, gcount);
    k_scanA<<<SCB, 256, 0, stream>>>(gcount, bsum);
    k_scanB<<<1, 256, 0, stream>>>(bsum, boff, row_ptr);
    k_scanC<<<SCB, 256, 0, stream>>>(gcount, boff);
    k_p1scat<<<P1B, 256, 0, stream>>>(src, dst, gcount, tmp);
    k_p2<<<NBUCK, 256, 0, stream>>>(tmp, gcount, row_ptr, csr_src);

    // vn/pooled init must precede the fused input-linear (its epilogue reads vn, pooled)
    k_vn_init<<<32, 256, 0, stream>>>(vn_emb, vn, pooled);
    // input linear + fused pre_0
    k_gemm_pre<0, 1, 1><<<GB, 256, 0, stream>>>(
        x, lin_W, lin_b, nullptr, nullptr, nullptr, nullptr,
        vn, batch_id, hb, out, pooled);

    for (int l = 0; l < 4; ++l) {   // layer 4's GINConv output is never used
        k_agg<<<N_NODES / 4, 256, 0, stream>>>(hb, row_ptr, csr_src, agg, eps, l);
        // z1 = relu(BN1(agg@W1+b1)); extra block: vn_{l+1} = MLP(pooled_l), pooled reset
        k_gemm1vn<<<GB + 1, 256, 0, stream>>>(agg, gin_W1 + l * 4096, gin_b1 + l * 64,
                                              gbn_g + l * 64, gbn_b + l * 64,
                                              gbn_m + l * 64, gbn_v + l * 64, z1,
                                              pooled,
                                              vn_W1 + l * 4096, vn_b1 + l * 64,
                                              v1g + l * 64, v1b + l * 64,
                                              v1m + l * 64, v1v + l * 64,
                                              vn_W2 + l * 4096, vn_b2 + l * 64,
                                              v2g + l * 64, v2b + l * 64,
                                              v2m + l * 64, v2v + l * 64,
                                              vn, pooled);
        // h_{l+1} = relu(BN2(z1@W2+b2)) with fused pre_{l+1} (uses vn_{l+1})
        if (l < 3) {
            k_gemm_pre<1, 0, 1><<<GB, 256, 0, stream>>>(
                z1, gin_W2 + l * 4096, gin_b2 + l * 64,
                bn_g + l * 64, bn_b + l * 64, bn_m + l * 64, bn_v + l * 64,
                vn, batch_id, hb, out, pooled);
        } else {
            k_gemm_pre<1, 0, 0><<<GB, 256, 0, stream>>>(
                z1, gin_W2 + l * 4096, gin_b2 + l * 64,
                bn_g + l * 64, bn_b + l * 64, bn_m + l * 64, bn_v + l * 64,
                vn, batch_id, hb, out, pooled);
        }
    }
}

// Round 9
// 711.525 us; speedup vs baseline: 2.6957x; 2.6957x over previous
//
#include <hip/hip_runtime.h>

#define N_NODES 50000
#define N_EDGES 1600000
#define NB 128
#define GB 782            // ceil(N/64)
#define P1B 196           // pass-1 blocks, 8192 edges each
#define P1E 8192
#define NBUCK 196         // dst >> 8 (256 nodes per bucket)
#define TOTG (NBUCK * P1B)   // 38416
#define SCB 151              // ceil(TOTG/256)

__device__ __forceinline__ unsigned short f2bf(float f) {
    unsigned u = __float_as_uint(f);
    unsigned r = (u + 0x7FFFu + ((u >> 16) & 1u)) >> 16;   // RNE
    return (unsigned short)r;
}

// ---------- CSR build: two-phase radix partition ----------
__global__ __launch_bounds__(256) void k_p1hist(
    const int* __restrict__ dst, int* __restrict__ gcount) {
    __shared__ int hist[NBUCK];
    int tid = threadIdx.x;
    if (tid < NBUCK) hist[tid] = 0;
    __syncthreads();
    int base = blockIdx.x * P1E;
    for (int k = 0; k < P1E; k += 256) {
        int e = base + k + tid;
        if (e < N_EDGES) atomicAdd(&hist[dst[e] >> 8], 1);
    }
    __syncthreads();
    if (tid < NBUCK) gcount[tid * P1B + blockIdx.x] = hist[tid];
}

__global__ __launch_bounds__(256) void k_scanA(
    const int* __restrict__ gcount, int* __restrict__ bsum) {
    int i = blockIdx.x * 256 + threadIdx.x;
    int v = (i < TOTG) ? gcount[i] : 0;
#pragma unroll
    for (int off = 1; off < 64; off <<= 1) v += __shfl_xor(v, off);
    __shared__ int ws[4];
    if ((threadIdx.x & 63) == 0) ws[threadIdx.x >> 6] = v;
    __syncthreads();
    if (threadIdx.x == 0) bsum[blockIdx.x] = ws[0] + ws[1] + ws[2] + ws[3];
}

__global__ __launch_bounds__(256) void k_scanB(
    const int* __restrict__ bsum, int* __restrict__ boff, int* __restrict__ row_ptr) {
    __shared__ int s[256];
    int t = threadIdx.x;
    int v = (t < SCB) ? bsum[t] : 0;
    s[t] = v;
    __syncthreads();
    for (int off = 1; off < 256; off <<= 1) {
        int x = s[t];
        int y = (t >= off) ? s[t - off] : 0;
        __syncthreads();
        s[t] = x + y;
        __syncthreads();
    }
    if (t < SCB) boff[t] = s[t] - v;
    if (t == 255) row_ptr[N_NODES] = s[255];
}

__global__ __launch_bounds__(256) void k_scanC(
    int* __restrict__ gcount, const int* __restrict__ boff) {
    __shared__ int s[256];
    int t = threadIdx.x;
    int i = blockIdx.x * 256 + t;
    int v = (i < TOTG) ? gcount[i] : 0;
    s[t] = v;
    __syncthreads();
    for (int off = 1; off < 256; off <<= 1) {
        int x = s[t];
        int y = (t >= off) ? s[t - off] : 0;
        __syncthreads();
        s[t] = x + y;
        __syncthreads();
    }
    if (i < TOTG) gcount[i] = s[t] - v + boff[blockIdx.x];
}

__global__ __launch_bounds__(256) void k_p1scat(
    const int* __restrict__ src, const int* __restrict__ dst,
    const int* __restrict__ goff, unsigned* __restrict__ tmp) {
    __shared__ int cur[NBUCK];
    int tid = threadIdx.x;
    if (tid < NBUCK) cur[tid] = goff[tid * P1B + blockIdx.x];
    __syncthreads();
    int base = blockIdx.x * P1E;
    for (int k = 0; k < P1E; k += 256) {
        int e = base + k + tid;
        if (e < N_EDGES) {
            int d = dst[e];
            int pos = atomicAdd(&cur[d >> 8], 1);
            tmp[pos] = ((unsigned)(d & 255) << 16) | (unsigned)src[e];
        }
    }
}

__global__ __launch_bounds__(256) void k_p2(
    const unsigned* __restrict__ tmp, const int* __restrict__ goff,
    int* __restrict__ row_ptr, unsigned short* __restrict__ csr_src) {
    __shared__ int nh[256];
    __shared__ int ps[256];
    int b = blockIdx.x, tid = threadIdx.x;
    int base = goff[b * P1B];
    int endv = (b == NBUCK - 1) ? N_EDGES : goff[(b + 1) * P1B];
    int cnt = endv - base;
    nh[tid] = 0;
    __syncthreads();
    for (int i = tid; i < cnt; i += 256)
        atomicAdd(&nh[tmp[base + i] >> 16], 1);
    __syncthreads();
    int deg = nh[tid];
    ps[tid] = deg;
    __syncthreads();
    for (int off = 1; off < 256; off <<= 1) {
        int x = ps[tid];
        int y = (tid >= off) ? ps[tid - off] : 0;
        __syncthreads();
        ps[tid] = x + y;
        __syncthreads();
    }
    int ex = ps[tid] - deg;
    int node = (b << 8) + tid;
    if (node < N_NODES) row_ptr[node] = base + ex;
    __syncthreads();
    nh[tid] = ex;   // cursor
    __syncthreads();
    for (int i = tid; i < cnt; i += 256) {
        unsigned u = tmp[base + i];
        int pos = atomicAdd(&nh[u >> 16], 1);
        csr_src[base + pos] = (unsigned short)(u & 0xFFFFu);
    }
}

// vn = pooled = broadcast(vn_emb)
__global__ __launch_bounds__(256) void k_vn_init(
    const float* __restrict__ vn_emb, float* __restrict__ vn,
    float* __restrict__ pooled) {
    int t = blockIdx.x * 256 + threadIdx.x;
    float v = vn_emb[t & 63];
    vn[t] = v;
    pooled[t] = v;
}

// agg[d] = (1+eps[l])*h[d] + sum over csr row of relu(h[src]); h stored bf16 (hb)
// one wave per node; lane = (e8 = lane>>3 edge slot, cg = lane&7 channel group)
__global__ __launch_bounds__(256) void k_agg(
    const unsigned short* __restrict__ hb,
    const int* __restrict__ row_ptr, const unsigned short* __restrict__ csr_src,
    float* __restrict__ agg, const float* __restrict__ eps, int l) {
    int wave = threadIdx.x >> 6, lane = threadIdx.x & 63;
    int node = blockIdx.x * 4 + wave;
    int s0 = row_ptr[node], s1 = row_ptr[node + 1];
    int e8 = lane >> 3, cg = lane & 7;
    float acc[8] = {0.f, 0.f, 0.f, 0.f, 0.f, 0.f, 0.f, 0.f};
    for (int e = s0 + e8; e < s1; e += 8) {
        int sidx = (int)csr_src[e];
        uint4 pk = *(const uint4*)(hb + (size_t)sidx * 64 + cg * 8);
        acc[0] += fmaxf(__uint_as_float(pk.x << 16), 0.f);
        acc[1] += fmaxf(__uint_as_float(pk.x & 0xFFFF0000u), 0.f);
        acc[2] += fmaxf(__uint_as_float(pk.y << 16), 0.f);
        acc[3] += fmaxf(__uint_as_float(pk.y & 0xFFFF0000u), 0.f);
        acc[4] += fmaxf(__uint_as_float(pk.z << 16), 0.f);
        acc[5] += fmaxf(__uint_as_float(pk.z & 0xFFFF0000u), 0.f);
        acc[6] += fmaxf(__uint_as_float(pk.w << 16), 0.f);
        acc[7] += fmaxf(__uint_as_float(pk.w & 0xFFFF0000u), 0.f);
    }
#pragma unroll
    for (int off = 8; off < 64; off <<= 1) {
#pragma unroll
        for (int c = 0; c < 8; ++c)
            acc[c] += __shfl_xor(acc[c], off);
    }
    if (e8 == 0) {
        float se = 1.0f + eps[l];
        uint4 hp = *(const uint4*)(hb + (size_t)node * 64 + cg * 8);
        float* ap = agg + (size_t)node * 64 + cg * 8;
        float4 o0, o1;
        o0.x = se * __uint_as_float(hp.x << 16)          + acc[0];
        o0.y = se * __uint_as_float(hp.x & 0xFFFF0000u)  + acc[1];
        o0.z = se * __uint_as_float(hp.y << 16)          + acc[2];
        o0.w = se * __uint_as_float(hp.y & 0xFFFF0000u)  + acc[3];
        o1.x = se * __uint_as_float(hp.z << 16)          + acc[4];
        o1.y = se * __uint_as_float(hp.z & 0xFFFF0000u)  + acc[5];
        o1.z = se * __uint_as_float(hp.w << 16)          + acc[6];
        o1.w = se * __uint_as_float(hp.w & 0xFFFF0000u)  + acc[7];
        *(float4*)(ap) = o0;
        *(float4*)(ap + 4) = o1;
    }
}

// GEMM + fused pre epilogue (compile-time specialized):
// o = HAS_BN ? relu(BN(in@W+bias)) : in@W+bias
// hv = o + vn[batch]; out = OUT_INIT ? hv : out+hv
// if FULL: hb = bf16(hv), pooled += segment_sum(hv)
// NOTE: plain __launch_bounds__(256) — an occupancy bound of 4 waves/EU (R8)
// capped VGPRs so hard the GEMM accumulators spilled to scratch (459 MB
// FETCH/dispatch). Specialized kernels fit ~90 VGPR unconstrained.
template <int HAS_BN, int OUT_INIT, int FULL>
__global__ __launch_bounds__(256) void k_gemm_pre(
    const float* __restrict__ in, const float* __restrict__ W,
    const float* __restrict__ bias,
    const float* __restrict__ g, const float* __restrict__ be,
    const float* __restrict__ m, const float* __restrict__ v,
    const float* __restrict__ vn, const int* __restrict__ batch_id,
    unsigned short* __restrict__ hb, float* __restrict__ out,
    float* __restrict__ pooled) {
    __shared__ float sW[64 * 64];
    __shared__ float sIn[64 * 68];
    int tid = threadIdx.x;
    int row0 = blockIdx.x * 64;
#pragma unroll
    for (int i = 0; i < 4; ++i)
        ((float4*)sW)[tid + 256 * i] = ((const float4*)W)[tid + 256 * i];
#pragma unroll
    for (int i = 0; i < 4; ++i) {
        int idx = tid + 256 * i;
        int r = idx >> 4, j = idx & 15;
        float4 val = make_float4(0.f, 0.f, 0.f, 0.f);
        if (row0 + r < N_NODES) val = ((const float4*)in)[(size_t)(row0 + r) * 16 + j];
        ((float4*)(sIn + r * 68))[j] = val;
    }
    __syncthreads();
    int c4 = (tid & 15) * 4;
    int rl = (tid >> 4) * 4;
    float acc[4][4] = {{0.f}};
    for (int k = 0; k < 64; k += 4) {
        float4 a[4];
#pragma unroll
        for (int i = 0; i < 4; ++i) a[i] = *(const float4*)(sIn + (rl + i) * 68 + k);
#pragma unroll
        for (int kk = 0; kk < 4; ++kk) {
            float4 wv = *(const float4*)(sW + (k + kk) * 64 + c4);
#pragma unroll
            for (int i = 0; i < 4; ++i) {
                float av = kk == 0 ? a[i].x : kk == 1 ? a[i].y : kk == 2 ? a[i].z : a[i].w;
                acc[i][0] += av * wv.x; acc[i][1] += av * wv.y;
                acc[i][2] += av * wv.z; acc[i][3] += av * wv.w;
            }
        }
    }
    float scl[4], shf[4];
#pragma unroll
    for (int j = 0; j < 4; ++j) {
        int c = c4 + j;
        if (HAS_BN) {
            float sc = g[c] * rsqrtf(v[c] + 1e-5f);
            scl[j] = sc;
            shf[j] = be[c] - m[c] * sc + bias[c] * sc;
        } else {
            scl[j] = 1.0f;
            shf[j] = bias[c];
        }
    }
    // ---- fused pre epilogue ----
    __syncthreads();                     // all GEMM reads of sIn done
    float* sP = sIn;                     // [16][64] pool partials
    int* sBid = (int*)(sIn + 1024);      // 64 ints
    if (tid < 64) {
        int row = row0 + tid;
        sBid[tid] = batch_id[row < N_NODES ? row : (N_NODES - 1)];
    }
    __syncthreads();
    bool fast = (sBid[0] == sBid[63]);
    float4 psum = make_float4(0.f, 0.f, 0.f, 0.f);
#pragma unroll
    for (int i = 0; i < 4; ++i) {
        int row = row0 + rl + i;
        if (row >= N_NODES) continue;
        float o0 = acc[i][0] * scl[0] + shf[0];
        float o1 = acc[i][1] * scl[1] + shf[1];
        float o2 = acc[i][2] * scl[2] + shf[2];
        float o3 = acc[i][3] * scl[3] + shf[3];
        if (HAS_BN) {
            o0 = fmaxf(o0, 0.f); o1 = fmaxf(o1, 0.f);
            o2 = fmaxf(o2, 0.f); o3 = fmaxf(o3, 0.f);
        }
        int b = sBid[rl + i];
        float4 vnv = *(const float4*)(vn + b * 64 + c4);
        float4 hv = make_float4(o0 + vnv.x, o1 + vnv.y, o2 + vnv.z, o3 + vnv.w);
        if (OUT_INIT) {
            *(float4*)(out + (size_t)row * 64 + c4) = hv;
        } else {
            float4 ov = *(const float4*)(out + (size_t)row * 64 + c4);
            ov.x += hv.x; ov.y += hv.y; ov.z += hv.z; ov.w += hv.w;
            *(float4*)(out + (size_t)row * 64 + c4) = ov;
        }
        if (FULL) {
            ushort4 rb;
            rb.x = f2bf(hv.x); rb.y = f2bf(hv.y);
            rb.z = f2bf(hv.z); rb.w = f2bf(hv.w);
            *(ushort4*)(hb + (size_t)row * 64 + c4) = rb;
            if (fast) {
                psum.x += hv.x; psum.y += hv.y; psum.z += hv.z; psum.w += hv.w;
            } else {
                atomicAdd(&pooled[b * 64 + c4 + 0], hv.x);
                atomicAdd(&pooled[b * 64 + c4 + 1], hv.y);
                atomicAdd(&pooled[b * 64 + c4 + 2], hv.z);
                atomicAdd(&pooled[b * 64 + c4 + 3], hv.w);
            }
        }
    }
    if (FULL && fast) {
        *(float4*)(sP + (tid >> 4) * 64 + c4) = psum;
        __syncthreads();
        if (tid < 64) {
            float s = 0.f;
#pragma unroll
            for (int r = 0; r < 16; ++r) s += sP[r * 64 + tid];
            atomicAdd(&pooled[sBid[0] * 64 + tid], s);
        }
    }
}

// GIN stage 1: z1 = relu(BN1(agg@W1+b1)); block GB runs the vn MLP
__global__ __launch_bounds__(256) void k_gemm1vn(
    const float* __restrict__ in, const float* __restrict__ W,
    const float* __restrict__ bias, const float* __restrict__ g,
    const float* __restrict__ be, const float* __restrict__ m,
    const float* __restrict__ v, float* __restrict__ out,
    const float* __restrict__ pooled,
    const float* __restrict__ W1, const float* __restrict__ b1,
    const float* __restrict__ g1, const float* __restrict__ be1,
    const float* __restrict__ m1, const float* __restrict__ v1,
    const float* __restrict__ W2, const float* __restrict__ b2,
    const float* __restrict__ g2, const float* __restrict__ be2,
    const float* __restrict__ m2, const float* __restrict__ v2,
    float* __restrict__ vn_out, float* __restrict__ pooled_out) {
    __shared__ float sW[64 * 64];
    __shared__ float sIn[64 * 68];
    int tid = threadIdx.x;
    int c4 = (tid & 15) * 4;
    int rl = (tid >> 4) * 4;

    if (blockIdx.x == GB) {
        for (int ph = 0; ph < 2; ++ph) {
#pragma unroll
            for (int i = 0; i < 4; ++i)
                ((float4*)sW)[tid + 256 * i] = ((const float4*)W1)[tid + 256 * i];
#pragma unroll
            for (int i = 0; i < 4; ++i) {
                int idx = tid + 256 * i;
                int r = idx >> 4, j = idx & 15;
                ((float4*)(sIn + r * 68))[j] = ((const float4*)pooled)[(ph * 64 + r) * 16 + j];
            }
            __syncthreads();
            float acc[4][4] = {{0.f}};
#pragma unroll 8
            for (int k = 0; k < 64; ++k) {
                float4 w = *(const float4*)(sW + k * 64 + c4);
#pragma unroll
                for (int i = 0; i < 4; ++i) {
                    float a = sIn[(rl + i) * 68 + k];
                    acc[i][0] += a * w.x; acc[i][1] += a * w.y;
                    acc[i][2] += a * w.z; acc[i][3] += a * w.w;
                }
            }
            float scl[4], shf[4];
#pragma unroll
            for (int j = 0; j < 4; ++j) {
                int c = c4 + j;
                float sc = g1[c] * rsqrtf(v1[c] + 1e-5f);
                scl[j] = sc;
                shf[j] = be1[c] - m1[c] * sc + b1[c] * sc;
            }
            __syncthreads();
#pragma unroll
            for (int i = 0; i < 4; ++i)
#pragma unroll
                for (int j = 0; j < 4; ++j)
                    sIn[(rl + i) * 68 + c4 + j] = fmaxf(acc[i][j] * scl[j] + shf[j], 0.f);
#pragma unroll
            for (int i = 0; i < 4; ++i)
                ((float4*)sW)[tid + 256 * i] = ((const float4*)W2)[tid + 256 * i];
            __syncthreads();
            float acc2[4][4] = {{0.f}};
#pragma unroll 8
            for (int k = 0; k < 64; ++k) {
                float4 w = *(const float4*)(sW + k * 64 + c4);
#pragma unroll
                for (int i = 0; i < 4; ++i) {
                    float a = sIn[(rl + i) * 68 + k];
                    acc2[i][0] += a * w.x; acc2[i][1] += a * w.y;
                    acc2[i][2] += a * w.z; acc2[i][3] += a * w.w;
                }
            }
#pragma unroll
            for (int j = 0; j < 4; ++j) {
                int c = c4 + j;
                float sc = g2[c] * rsqrtf(v2[c] + 1e-5f);
                scl[j] = sc;
                shf[j] = be2[c] - m2[c] * sc + b2[c] * sc;
            }
#pragma unroll
            for (int i = 0; i < 4; ++i) {
                int row = ph * 64 + rl + i;
                float4 o;
                o.x = fmaxf(acc2[i][0] * scl[0] + shf[0], 0.f);
                o.y = fmaxf(acc2[i][1] * scl[1] + shf[1], 0.f);
                o.z = fmaxf(acc2[i][2] * scl[2] + shf[2], 0.f);
                o.w = fmaxf(acc2[i][3] * scl[3] + shf[3], 0.f);
                *(float4*)(vn_out + row * 64 + c4) = o;
                *(float4*)(pooled_out + row * 64 + c4) = o;
            }
            __syncthreads();
        }
        return;
    }

    int row0 = blockIdx.x * 64;
#pragma unroll
    for (int i = 0; i < 4; ++i)
        ((float4*)sW)[tid + 256 * i] = ((const float4*)W)[tid + 256 * i];
#pragma unroll
    for (int i = 0; i < 4; ++i) {
        int idx = tid + 256 * i;
        int r = idx >> 4, j = idx & 15;
        float4 val = make_float4(0.f, 0.f, 0.f, 0.f);
        if (row0 + r < N_NODES) val = ((const float4*)in)[(size_t)(row0 + r) * 16 + j];
        ((float4*)(sIn + r * 68))[j] = val;
    }
    __syncthreads();
    float acc[4][4] = {{0.f}};
    for (int k = 0; k < 64; k += 4) {
        float4 a[4];
#pragma unroll
        for (int i = 0; i < 4; ++i) a[i] = *(const float4*)(sIn + (rl + i) * 68 + k);
#pragma unroll
        for (int kk = 0; kk < 4; ++kk) {
            float4 wv = *(const float4*)(sW + (k + kk) * 64 + c4);
#pragma unroll
            for (int i = 0; i < 4; ++i) {
                float av = kk == 0 ? a[i].x : kk == 1 ? a[i].y : kk == 2 ? a[i].z : a[i].w;
                acc[i][0] += av * wv.x; acc[i][1] += av * wv.y;
                acc[i][2] += av * wv.z; acc[i][3] += av * wv.w;
            }
        }
    }
    float scl[4], shf[4];
#pragma unroll
    for (int j = 0; j < 4; ++j) {
        int c = c4 + j;
        float sc = g[c] * rsqrtf(v[c] + 1e-5f);
        scl[j] = sc;
        shf[j] = be[c] - m[c] * sc + bias[c] * sc;
    }
#pragma unroll
    for (int r = 0; r < 4; ++r) {
        int row = row0 + rl + r;
        if (row < N_NODES) {
            float4 o;
            o.x = fmaxf(acc[r][0] * scl[0] + shf[0], 0.f);
            o.y = fmaxf(acc[r][1] * scl[1] + shf[1], 0.f);
            o.z = fmaxf(acc[r][2] * scl[2] + shf[2], 0.f);
            o.w = fmaxf(acc[r][3] * scl[3] + shf[3], 0.f);
            *(float4*)(out + (size_t)row * 64 + c4) = o;
        }
    }
}

extern "C" void kernel_launch(void* const* d_in, const int* in_sizes, int n_in,
                              void* d_out, int out_size, void* d_ws, size_t ws_size,
                              hipStream_t stream) {
    const float* x      = (const float*)d_in[0];
    const float* lin_W  = (const float*)d_in[1];
    const float* lin_b  = (const float*)d_in[2];
    const float* eps    = (const float*)d_in[3];
    const float* gin_W1 = (const float*)d_in[4];
    const float* gin_b1 = (const float*)d_in[5];
    const float* gbn_g  = (const float*)d_in[6];
    const float* gbn_b  = (const float*)d_in[7];
    const float* gbn_m  = (const float*)d_in[8];
    const float* gbn_v  = (const float*)d_in[9];
    const float* gin_W2 = (const float*)d_in[10];
    const float* gin_b2 = (const float*)d_in[11];
    const float* bn_g   = (const float*)d_in[12];
    const float* bn_b   = (const float*)d_in[13];
    const float* bn_m   = (const float*)d_in[14];
    const float* bn_v   = (const float*)d_in[15];
    const float* vn_emb = (const float*)d_in[16];
    const float* vn_W1  = (const float*)d_in[17];
    const float* vn_b1  = (const float*)d_in[18];
    const float* v1g    = (const float*)d_in[19];
    const float* v1b    = (const float*)d_in[20];
    const float* v1m    = (const float*)d_in[21];
    const float* v1v    = (const float*)d_in[22];
    const float* vn_W2  = (const float*)d_in[23];
    const float* vn_b2  = (const float*)d_in[24];
    const float* v2g    = (const float*)d_in[25];
    const float* v2b    = (const float*)d_in[26];
    const float* v2m    = (const float*)d_in[27];
    const float* v2v    = (const float*)d_in[28];
    const int* src      = (const int*)d_in[29];
    const int* dst      = (const int*)d_in[30];
    const int* batch_id = (const int*)d_in[31];
    float* out = (float*)d_out;

    // workspace layout (16B-aligned regions)
    unsigned short* hb = (unsigned short*)d_ws;            // N*64 bf16 (h)
    float* z1     = (float*)(hb + (size_t)N_NODES * 64);   // N*64 f32
    float* agg    = z1 + (size_t)N_NODES * 64;             // N*64 f32
    float* vn     = agg + (size_t)N_NODES * 64;            // B*64
    float* pooled = vn + (size_t)NB * 64;                  // B*64
    int*   gcount  = (int*)(pooled + (size_t)NB * 64);     // TOTG
    int*   row_ptr = gcount + TOTG;                        // N+1
    int*   bsum    = row_ptr + N_NODES + 2;                // 256
    int*   boff    = bsum + 256;                           // 256
    unsigned* tmp  = (unsigned*)(boff + 256);              // E u32
    unsigned short* csr_src = (unsigned short*)(tmp + N_EDGES); // E ushort

    // ---- CSR build (radix partition; single-owner final writes) ----
    k_p1hist<<<P1B, 256, 0, stream>>>(dst, gcount);
    k_scanA<<<SCB, 256, 0, stream>>>(gcount, bsum);
    k_scanB<<<1, 256, 0, stream>>>(bsum, boff, row_ptr);
    k_scanC<<<SCB, 256, 0, stream>>>(gcount, boff);
    k_p1scat<<<P1B, 256, 0, stream>>>(src, dst, gcount, tmp);
    k_p2<<<NBUCK, 256, 0, stream>>>(tmp, gcount, row_ptr, csr_src);

    // vn/pooled init must precede the fused input-linear (its epilogue reads vn, pooled)
    k_vn_init<<<32, 256, 0, stream>>>(vn_emb, vn, pooled);
    // input linear + fused pre_0
    k_gemm_pre<0, 1, 1><<<GB, 256, 0, stream>>>(
        x, lin_W, lin_b, nullptr, nullptr, nullptr, nullptr,
        vn, batch_id, hb, out, pooled);

    for (int l = 0; l < 4; ++l) {   // layer 4's GINConv output is never used
        k_agg<<<N_NODES / 4, 256, 0, stream>>>(hb, row_ptr, csr_src, agg, eps, l);
        // z1 = relu(BN1(agg@W1+b1)); extra block: vn_{l+1} = MLP(pooled_l), pooled reset
        k_gemm1vn<<<GB + 1, 256, 0, stream>>>(agg, gin_W1 + l * 4096, gin_b1 + l * 64,
                                              gbn_g + l * 64, gbn_b + l * 64,
                                              gbn_m + l * 64, gbn_v + l * 64, z1,
                                              pooled,
                                              vn_W1 + l * 4096, vn_b1 + l * 64,
                                              v1g + l * 64, v1b + l * 64,
                                              v1m + l * 64, v1v + l * 64,
                                              vn_W2 + l * 4096, vn_b2 + l * 64,
                                              v2g + l * 64, v2b + l * 64,
                                              v2m + l * 64, v2v + l * 64,
                                              vn, pooled);
        // h_{l+1} = relu(BN2(z1@W2+b2)) with fused pre_{l+1} (uses vn_{l+1})
        if (l < 3) {
            k_gemm_pre<1, 0, 1><<<GB, 256, 0, stream>>>(
                z1, gin_W2 + l * 4096, gin_b2 + l * 64,
                bn_g + l * 64, bn_b + l * 64, bn_m + l * 64, bn_v + l * 64,
                vn, batch_id, hb, out, pooled);
        } else {
            k_gemm_pre<1, 0, 0><<<GB, 256, 0, stream>>>(
                z1, gin_W2 + l * 4096, gin_b2 + l * 64,
                bn_g + l * 64, bn_b + l * 64, bn_m + l * 64, bn_v + l * 64,
                vn, batch_id, hb, out, pooled);
        }
    }
}